// Round 4
// baseline (218.802 us; speedup 1.0000x reference)
//
#include <hip/hip_runtime.h>
#include <stdint.h>

// B=16, CIN=512, COUT=128, H=W=64
#define NB    16
#define CIN   512
#define COUT  128
#define HW    4096
#define NIT   16              // K-steps of 32

using bf16x8  = __attribute__((ext_vector_type(8))) __bf16;
using floatx4 = __attribute__((ext_vector_type(4))) float;

// RNE float -> bf16 bits (proven in R1-R3)
__device__ __forceinline__ unsigned short f2bf_bits(float f) {
    union { float f; unsigned u; } v; v.f = f;
    return (unsigned short)((v.u + 0x7fffu + ((v.u >> 16) & 1u)) >> 16);
}

// ---------------------------------------------------------------------------
// Precompute mw[b][k8][m][j] = bf16(weight[m][k8*8+j] * style[b][k8*8+j])
// Layout IS the 16x16x32 A-fragment layout: lane(m=l15,quad) reads 16B at
// ((k8)*128 + m)*8 — one coalesced dwordx4 per fragment.
// ---------------------------------------------------------------------------
__global__ __launch_bounds__(256)
void modw_kernel(const float* __restrict__ style,
                 const float* __restrict__ weight,
                 __bf16* __restrict__ mw)
{
    const int id = blockIdx.x * 256 + threadIdx.x;   // 512 blocks
    const int k8 = id & 63;
    const int m  = (id >> 6) & 127;
    const int b  = id >> 13;

    const float4 w0 = *(const float4*)(weight + m * CIN + k8 * 8);
    const float4 w1 = *(const float4*)(weight + m * CIN + k8 * 8 + 4);
    const float4 s0 = *(const float4*)(style + b * CIN + k8 * 8);
    const float4 s1 = *(const float4*)(style + b * CIN + k8 * 8 + 4);

    union { unsigned short us[8]; bf16x8 v; } pk;
    pk.us[0] = f2bf_bits(w0.x * s0.x);
    pk.us[1] = f2bf_bits(w0.y * s0.y);
    pk.us[2] = f2bf_bits(w0.z * s0.z);
    pk.us[3] = f2bf_bits(w0.w * s0.w);
    pk.us[4] = f2bf_bits(w1.x * s1.x);
    pk.us[5] = f2bf_bits(w1.y * s1.y);
    pk.us[6] = f2bf_bits(w1.z * s1.z);
    pk.us[7] = f2bf_bits(w1.w * s1.w);
    *(bf16x8*)(mw + ((size_t)(b * 64 + k8) * 128 + m) * 8) = pk.v;
}

// ---------------------------------------------------------------------------
// Barrier-free streaming GEMM. One wave owns a 64(m) x 32(n) output tile and
// iterates K in steps of 32, loading MFMA fragments DIRECTLY from global into
// registers (no LDS, no __syncthreads) with a depth-2 software pipeline, so
// the compiler's fine-grained vmcnt scheduling hides HBM latency.
// Waves 2w/2w+1 of a block share the same n-tile (m-halves) -> x fetched from
// HBM once, second read L1/L2-hit.
// ---------------------------------------------------------------------------
__global__ __launch_bounds__(256, 4)
void modconv1x1_kernel(const float* __restrict__ x,
                       const __bf16* __restrict__ mw,
                       float* __restrict__ out)
{
    const int tid  = threadIdx.x;
    const int lane = tid & 63;
    const int wave = tid >> 6;
    const int quad = lane >> 4;
    const int l15  = lane & 15;

    const int b     = blockIdx.x >> 6;                 // batch
    const int idx   = (blockIdx.x & 63) * 4 + wave;    // 0..255 per batch
    const int mhalf = idx & 1;
    const int n0    = (idx >> 1) * 32;                 // 128 n-tiles of 32
    const int wm    = mhalf * 64;

    const float*  xb   = x   + (size_t)b * CIN * HW + n0;
    float*        outb = out + (size_t)b * COUT * HW + n0;
    const __bf16* mwb  = mw  + (size_t)b * (64 * 128 * 8);

    floatx4 acc[4][2];
    #pragma unroll
    for (int i = 0; i < 4; ++i)
        #pragma unroll
        for (int j = 0; j < 2; ++j)
            acc[i][j] = (floatx4){0.f, 0.f, 0.f, 0.f};

    bf16x8 afA[2][4];     // A fragments, 2 pipeline stages
    float  rbf[2][16];    // B fp32 staging, 2 pipeline stages

#define LOAD_STAGE(S, ST)                                                      \
    {                                                                          \
        const __bf16* abase = mwb + (size_t)((4 * (S) + quad) * 128) * 8;      \
        _Pragma("unroll")                                                      \
        for (int tm = 0; tm < 4; ++tm)                                         \
            afA[ST][tm] = *(const bf16x8*)(abase + (wm + tm * 16 + l15) * 8);  \
        const float* src = xb + (size_t)((4 * (S) + quad) * 8) * HW + l15;     \
        _Pragma("unroll")                                                      \
        for (int tn = 0; tn < 2; ++tn)                                         \
            _Pragma("unroll")                                                  \
            for (int j = 0; j < 8; ++j)                                        \
                rbf[ST][tn * 8 + j] = src[(size_t)j * HW + tn * 16];           \
    }

    // prologue: stage 0
    LOAD_STAGE(0, 0)

    for (int s = 0; s < NIT; ++s) {
        const int cur = s & 1;
        if (s + 1 < NIT) LOAD_STAGE(s + 1, cur ^ 1)

        // convert B staging -> fragments (RNE), then 8 MFMAs
        bf16x8 bfr[2];
        #pragma unroll
        for (int tn = 0; tn < 2; ++tn) {
            union { unsigned short us[8]; bf16x8 v; } pk;
            #pragma unroll
            for (int j = 0; j < 8; ++j)
                pk.us[j] = f2bf_bits(rbf[cur][tn * 8 + j]);
            bfr[tn] = pk.v;
        }
        #pragma unroll
        for (int tm = 0; tm < 4; ++tm)
            #pragma unroll
            for (int tn = 0; tn < 2; ++tn)
                acc[tm][tn] = __builtin_amdgcn_mfma_f32_16x16x32_bf16(
                    afA[cur][tm], bfr[tn], acc[tm][tn], 0, 0, 0);
    }
#undef LOAD_STAGE

    // epilogue: C/D layout col(n)=l15, row(o)=quad*4+reg
    #pragma unroll
    for (int tm = 0; tm < 4; ++tm) {
        const int o = wm + tm * 16 + quad * 4;
        #pragma unroll
        for (int tn = 0; tn < 2; ++tn) {
            const int n = tn * 16 + l15;
            #pragma unroll
            for (int r = 0; r < 4; ++r)
                outb[(size_t)(o + r) * HW + n] = acc[tm][tn][r];
        }
    }
}

extern "C" void kernel_launch(void* const* d_in, const int* in_sizes, int n_in,
                              void* d_out, int out_size, void* d_ws, size_t ws_size,
                              hipStream_t stream) {
    const float* x      = (const float*)d_in[0];   // (16, 512, 64, 64) fp32
    const float* style  = (const float*)d_in[1];   // (16, 512) fp32
    const float* weight = (const float*)d_in[2];   // (128, 512) fp32
    float* out = (float*)d_out;                    // (16, 128, 64, 64) fp32
    __bf16* mw = (__bf16*)d_ws;                    // 2 MB modulated weights

    modw_kernel<<<dim3(512), dim3(256), 0, stream>>>(style, weight, mw);
    modconv1x1_kernel<<<dim3(NB * 64), dim3(256), 0, stream>>>(x, mw, out);
}

// Round 5
// 210.862 us; speedup vs baseline: 1.0377x; 1.0377x over previous
//
#include <hip/hip_runtime.h>
#include <stdint.h>

// B=16, CIN=512, COUT=128, H=W=64
#define NB    16
#define CIN   512
#define COUT  128
#define HW    4096
#define BN    64              // N-tile per block
#define BK    32              // K-tile per iteration
#define NIT   (CIN / BK)      // 16
// grid = 16 b x 64 n-tiles = 1024 blocks = 4 blocks/CU

using bf16x8  = __attribute__((ext_vector_type(8))) __bf16;
using floatx4 = __attribute__((ext_vector_type(4))) float;

// RNE float -> bf16 bits (proven R1-R4)
__device__ __forceinline__ unsigned short f2bf_bits(float f) {
    union { float f; unsigned u; } v; v.f = f;
    return (unsigned short)((v.u + 0x7fffu + ((v.u >> 16) & 1u)) >> 16);
}

// async global->LDS, 16B/lane; LDS dest = wave-uniform base + lane*16
#define GLD16(g, l)                                                            \
    __builtin_amdgcn_global_load_lds(                                          \
        (const __attribute__((address_space(1))) void*)(g),                    \
        (__attribute__((address_space(3))) void*)(l), 16, 0, 0)

// ---------------------------------------------------------------------------
// Precompute mw[b][k8][m][j] = bf16(weight[m][k8*8+j] * style[b][k8*8+j])
// = the 16x16x32 A-fragment layout, contiguous per 8KB K-tile slab.
// ---------------------------------------------------------------------------
__global__ __launch_bounds__(256)
void modw_kernel(const float* __restrict__ style,
                 const float* __restrict__ weight,
                 __bf16* __restrict__ mw)
{
    const int id = blockIdx.x * 256 + threadIdx.x;   // 512 blocks
    const int k8 = id & 63;
    const int m  = (id >> 6) & 127;
    const int b  = id >> 13;

    const float4 w0 = *(const float4*)(weight + m * CIN + k8 * 8);
    const float4 w1 = *(const float4*)(weight + m * CIN + k8 * 8 + 4);
    const float4 s0 = *(const float4*)(style + b * CIN + k8 * 8);
    const float4 s1 = *(const float4*)(style + b * CIN + k8 * 8 + 4);

    union { unsigned short us[8]; bf16x8 v; } pk;
    pk.us[0] = f2bf_bits(w0.x * s0.x);
    pk.us[1] = f2bf_bits(w0.y * s0.y);
    pk.us[2] = f2bf_bits(w0.z * s0.z);
    pk.us[3] = f2bf_bits(w0.w * s0.w);
    pk.us[4] = f2bf_bits(w1.x * s1.x);
    pk.us[5] = f2bf_bits(w1.y * s1.y);
    pk.us[6] = f2bf_bits(w1.z * s1.z);
    pk.us[7] = f2bf_bits(w1.w * s1.w);
    *(bf16x8*)(mw + ((size_t)(b * 64 + k8) * 128 + m) * 8) = pk.v;
}

// ---------------------------------------------------------------------------
// Main GEMM, R3 structure but ALL global reads 16 B/lane via global_load_lds:
//  A: mw bf16 fragment slabs (2 GLDs/wave/step, L2-resident)
//  B: x fp32 rows straight to LDS (2 GLDs/wave/step, 4x256B segments each);
//     lane-linear image == row-major [k][n] stride-64 — no pad needed.
// B fragments: 16 ds_read_b32 + f2bf convert in regs per wave-step.
// ---------------------------------------------------------------------------
__global__ __launch_bounds__(256, 4)
void modconv1x1_kernel(const float* __restrict__ x,
                       const __bf16* __restrict__ mw,
                       float* __restrict__ out)
{
    __shared__ __align__(16) __bf16 Alds[2][4096];      // [k8][m][j], 2 x 8 KB
    __shared__ __align__(16) float  Blds[2][BK * BN];   // [k][n] stride 64, 2 x 8 KB

    const int tid  = threadIdx.x;
    const int lane = tid & 63;
    const int wave = tid >> 6;
    const int quad = lane >> 4;
    const int l15  = lane & 15;

    const int b  = blockIdx.x >> 6;
    const int n0 = (blockIdx.x & 63) * BN;

    const char*  xbb  = (const char*)(x + (size_t)b * CIN * HW + n0);
    float*       outb = out + (size_t)b * COUT * HW + n0;
    const char*  mwb  = (const char*)mw + (size_t)b * (64 * 128 * 16);  // 128KB/batch

    const int wm = (wave & 1) * 64;     // wave tile 64(m) x 32(n)
    const int wn = (wave >> 1) * 32;

    // B GLD lane geometry: 4 rows x 16 float4-cols per instruction
    const int brow = lane >> 4;         // 0..3
    const int bcol = lane & 15;         // float4 column

    floatx4 acc[4][2];
    #pragma unroll
    for (int i = 0; i < 4; ++i)
        #pragma unroll
        for (int j = 0; j < 2; ++j)
            acc[i][j] = (floatx4){0.f, 0.f, 0.f, 0.f};

#define STAGE(K0, BUF)                                                         \
    {                                                                          \
        const char* at = mwb + (size_t)(K0) * 256;                             \
        char*       al = (char*)&Alds[BUF][0];                                 \
        GLD16(at + wave * 2048 + lane * 16,        al + wave * 2048);          \
        GLD16(at + wave * 2048 + 1024 + lane * 16, al + wave * 2048 + 1024);   \
        char* bl = (char*)&Blds[BUF][0];                                       \
        _Pragma("unroll")                                                      \
        for (int g = 0; g < 2; ++g) {                                          \
            const int r = wave * 8 + g * 4 + brow;                             \
            GLD16(xbb + (size_t)((K0) + r) * (HW * 4) + bcol * 16,             \
                  bl + (wave * 8 + g * 4) * 256);                              \
        }                                                                      \
    }

    // prologue: tile 0 -> buf 0
    STAGE(0, 0)

    int cur = 0;
    for (int it = 0; it < NIT; ++it) {
        __syncthreads();   // buf[cur] complete; prev reads of buf[cur^1] done

        if (it + 1 < NIT) STAGE((it + 1) * BK, cur ^ 1)

        // A fragments: 4x ds_read_b128
        bf16x8 af[4];
        #pragma unroll
        for (int tm = 0; tm < 4; ++tm)
            af[tm] = *(const bf16x8*)&Alds[cur][(quad * COUT + wm + tm * 16 + l15) * 8];

        // B fragments: 16x ds_read_b32 + convert
        bf16x8 bfr[2];
        #pragma unroll
        for (int tn = 0; tn < 2; ++tn) {
            union { unsigned short us[8]; bf16x8 v; } pk;
            #pragma unroll
            for (int j = 0; j < 8; ++j)
                pk.us[j] = f2bf_bits(Blds[cur][(quad * 8 + j) * BN + wn + tn * 16 + l15]);
            bfr[tn] = pk.v;
        }

        #pragma unroll
        for (int tm = 0; tm < 4; ++tm)
            #pragma unroll
            for (int tn = 0; tn < 2; ++tn)
                acc[tm][tn] = __builtin_amdgcn_mfma_f32_16x16x32_bf16(
                    af[tm], bfr[tn], acc[tm][tn], 0, 0, 0);

        cur ^= 1;
    }
#undef STAGE

    // epilogue: C/D layout col(n)=l15, row(o)=quad*4+reg
    #pragma unroll
    for (int tm = 0; tm < 4; ++tm) {
        const int o = wm + tm * 16 + quad * 4;
        #pragma unroll
        for (int tn = 0; tn < 2; ++tn) {
            const int n = wn + tn * 16 + l15;
            #pragma unroll
            for (int r = 0; r < 4; ++r)
                outb[(size_t)(o + r) * HW + n] = acc[tm][tn][r];
        }
    }
}

extern "C" void kernel_launch(void* const* d_in, const int* in_sizes, int n_in,
                              void* d_out, int out_size, void* d_ws, size_t ws_size,
                              hipStream_t stream) {
    const float* x      = (const float*)d_in[0];   // (16, 512, 64, 64) fp32
    const float* style  = (const float*)d_in[1];   // (16, 512) fp32
    const float* weight = (const float*)d_in[2];   // (128, 512) fp32
    float* out = (float*)d_out;                    // (16, 128, 64, 64) fp32
    __bf16* mw = (__bf16*)d_ws;                    // 2 MB modulated weights

    modw_kernel<<<dim3(512), dim3(256), 0, stream>>>(style, weight, mw);
    modconv1x1_kernel<<<dim3(NB * 64), dim3(256), 0, stream>>>(x, mw, out);
}

// Round 6
// 206.943 us; speedup vs baseline: 1.0573x; 1.0189x over previous
//
#include <hip/hip_runtime.h>
#include <stdint.h>

// B=16, CIN=512, COUT=128, H=W=64
#define NB    16
#define CIN   512
#define COUT  128
#define HW    4096
#define BN    128             // N-tile per block (512B row-chunks)
#define BK    32              // K-tile per iteration
#define NIT   (CIN / BK)      // 16
// grid = 16 b x 32 n-tiles = 512 blocks x 512 thr = 2 blocks/CU

using bf16x8  = __attribute__((ext_vector_type(8))) __bf16;
using floatx4 = __attribute__((ext_vector_type(4))) float;

// RNE float -> bf16 bits (proven R1-R5)
__device__ __forceinline__ unsigned short f2bf_bits(float f) {
    union { float f; unsigned u; } v; v.f = f;
    return (unsigned short)((v.u + 0x7fffu + ((v.u >> 16) & 1u)) >> 16);
}

// async global->LDS, 16B/lane; LDS dest = wave-uniform base + lane*16,
// global address is per-lane (arbitrary gather).
#define GLD16(g, l)                                                            \
    __builtin_amdgcn_global_load_lds(                                          \
        (const __attribute__((address_space(1))) void*)(g),                    \
        (__attribute__((address_space(3))) void*)(l), 16, 0, 0)

// ---------------------------------------------------------------------------
// Precompute mw[b][k8][m][j] = bf16(weight[m][k8*8+j] * style[b][k8*8+j])
// = the 16x16x32 A-fragment layout, contiguous 8KB slab per K-tile.
// ---------------------------------------------------------------------------
__global__ __launch_bounds__(256)
void modw_kernel(const float* __restrict__ style,
                 const float* __restrict__ weight,
                 __bf16* __restrict__ mw)
{
    const int id = blockIdx.x * 256 + threadIdx.x;   // 512 blocks
    const int k8 = id & 63;
    const int m  = (id >> 6) & 127;
    const int b  = id >> 13;

    const float4 w0 = *(const float4*)(weight + m * CIN + k8 * 8);
    const float4 w1 = *(const float4*)(weight + m * CIN + k8 * 8 + 4);
    const float4 s0 = *(const float4*)(style + b * CIN + k8 * 8);
    const float4 s1 = *(const float4*)(style + b * CIN + k8 * 8 + 4);

    union { unsigned short us[8]; bf16x8 v; } pk;
    pk.us[0] = f2bf_bits(w0.x * s0.x);
    pk.us[1] = f2bf_bits(w0.y * s0.y);
    pk.us[2] = f2bf_bits(w0.z * s0.z);
    pk.us[3] = f2bf_bits(w0.w * s0.w);
    pk.us[4] = f2bf_bits(w1.x * s1.x);
    pk.us[5] = f2bf_bits(w1.y * s1.y);
    pk.us[6] = f2bf_bits(w1.z * s1.z);
    pk.us[7] = f2bf_bits(w1.w * s1.w);
    *(bf16x8*)(mw + ((size_t)(b * 64 + k8) * 128 + m) * 8) = pk.v;
}

// ---------------------------------------------------------------------------
// 128x128 block tile, 512 threads (8 waves of 64x32), dbuf LDS, 1 barrier/it.
// x read in 512B contiguous row-chunks (2 chunks = 1KB per GLD16 instr).
// ---------------------------------------------------------------------------
__global__ __launch_bounds__(512, 4)
void modconv1x1_kernel(const float* __restrict__ x,
                       const __bf16* __restrict__ mw,
                       float* __restrict__ out)
{
    __shared__ __align__(16) __bf16 Alds[2][4096];      // [k8][m][j]  2 x 8 KB
    __shared__ __align__(16) float  Blds[2][BK * BN];   // [k][n]      2 x 16 KB

    const int tid  = threadIdx.x;
    const int lane = tid & 63;
    const int wave = tid >> 6;          // 0..7
    const int quad = lane >> 4;
    const int l15  = lane & 15;

    const int b  = blockIdx.x >> 5;
    const int n0 = (blockIdx.x & 31) * BN;

    const char*  xbb  = (const char*)(x + (size_t)b * CIN * HW + n0);
    float*       outb = out + (size_t)b * COUT * HW + n0;
    const char*  mwb  = (const char*)mw + (size_t)b * (64 * 128 * 16);  // 128KB/batch

    const int wm = (wave & 1) * 64;     // wave tile 64(m) x 32(n)
    const int wn = (wave >> 1) * 32;

    // B GLD geometry: instr g covers rows 2g,2g+1 (512B each).
    const int brsel = lane >> 5;        // 0/1: which of the two rows
    const int bcol  = lane & 31;        // float4 column within row

    floatx4 acc[4][2];
    #pragma unroll
    for (int i = 0; i < 4; ++i)
        #pragma unroll
        for (int j = 0; j < 2; ++j)
            acc[i][j] = (floatx4){0.f, 0.f, 0.f, 0.f};

#define STAGE(K0, BUF)                                                         \
    {                                                                          \
        const char* at = mwb + (size_t)(K0) * 256;                             \
        char*       al = (char*)&Alds[BUF][0];                                 \
        GLD16(at + wave * 1024 + lane * 16, al + wave * 1024);                 \
        char* bl = (char*)&Blds[BUF][0];                                       \
        _Pragma("unroll")                                                      \
        for (int g = 0; g < 2; ++g) {                                          \
            const int gi = wave * 2 + g;              /* 0..15 */              \
            const int r  = gi * 2 + brsel;            /* row 0..31 */          \
            GLD16(xbb + (size_t)((K0) + r) * (HW * 4) + bcol * 16,             \
                  bl + gi * 1024);                                             \
        }                                                                      \
    }

    // prologue: tile 0 -> buf 0
    STAGE(0, 0)

    int cur = 0;
    for (int it = 0; it < NIT; ++it) {
        __syncthreads();   // buf[cur] complete; prior reads of buf[cur^1] done

        if (it + 1 < NIT) STAGE((it + 1) * BK, cur ^ 1)

        // A fragments: 4x ds_read_b128
        bf16x8 af[4];
        #pragma unroll
        for (int tm = 0; tm < 4; ++tm)
            af[tm] = *(const bf16x8*)&Alds[cur][(quad * COUT + wm + tm * 16 + l15) * 8];

        // B fragments: 16x ds_read_b32 + RNE convert
        bf16x8 bfr[2];
        #pragma unroll
        for (int tn = 0; tn < 2; ++tn) {
            union { unsigned short us[8]; bf16x8 v; } pk;
            #pragma unroll
            for (int j = 0; j < 8; ++j)
                pk.us[j] = f2bf_bits(Blds[cur][(quad * 8 + j) * BN + wn + tn * 16 + l15]);
            bfr[tn] = pk.v;
        }

        #pragma unroll
        for (int tm = 0; tm < 4; ++tm)
            #pragma unroll
            for (int tn = 0; tn < 2; ++tn)
                acc[tm][tn] = __builtin_amdgcn_mfma_f32_16x16x32_bf16(
                    af[tm], bfr[tn], acc[tm][tn], 0, 0, 0);

        cur ^= 1;
    }
#undef STAGE

    // epilogue: C/D layout col(n)=l15, row(o)=quad*4+reg
    #pragma unroll
    for (int tm = 0; tm < 4; ++tm) {
        const int o = wm + tm * 16 + quad * 4;
        #pragma unroll
        for (int tn = 0; tn < 2; ++tn) {
            const int n = wn + tn * 16 + l15;
            #pragma unroll
            for (int r = 0; r < 4; ++r)
                outb[(size_t)(o + r) * HW + n] = acc[tm][tn][r];
        }
    }
}

extern "C" void kernel_launch(void* const* d_in, const int* in_sizes, int n_in,
                              void* d_out, int out_size, void* d_ws, size_t ws_size,
                              hipStream_t stream) {
    const float* x      = (const float*)d_in[0];   // (16, 512, 64, 64) fp32
    const float* style  = (const float*)d_in[1];   // (16, 512) fp32
    const float* weight = (const float*)d_in[2];   // (128, 512) fp32
    float* out = (float*)d_out;                    // (16, 128, 64, 64) fp32
    __bf16* mw = (__bf16*)d_ws;                    // 2 MB modulated weights

    modw_kernel<<<dim3(512), dim3(256), 0, stream>>>(style, weight, mw);
    modconv1x1_kernel<<<dim3(NB * 32), dim3(512), 0, stream>>>(x, mw, out);
}